// Round 11
// baseline (220.274 us; speedup 1.0000x reference)
//
#include <hip/hip_runtime.h>
#include <hip/hip_fp16.h>
#include <stdint.h>
#include <math.h>

#define NEG_SLOPE 0.2f

static __device__ __forceinline__ unsigned short f2bf(float f) {
    unsigned u = __float_as_uint(f);
    unsigned r = (u + 0x7FFFu + ((u >> 16) & 1u)) >> 16;
    return (unsigned short)r;
}
static __device__ __forceinline__ unsigned pack_h2(float a, float b) {
    __half2 h = __floats2half2_rn(a, b);
    return *(unsigned*)&h;
}

// LEDGER (do not re-try):
//  - (256,6) launch bounds: VGPR capped at 40 → acc spills (r1).
//  - 4 B bucket entries + erec: scattered stores cost a 64 B line each;
//    CROSS-XCD entries never merge (r2). 16 B inline entry optimal.
//  - W^T LDS swizzle: bank conflicts (r3). Keep wS[k][col].
//  - Kernel split (r4): +28 us; edge must stay fused. gemm standalone 52 us,
//    6% HBM / 33% VALU / 18.8% occ → latency-bound.
//  - b128 W-reads (r5): −2 us. Best k1 = 60.2 us.
//  - Reg double-buffer (r6): spills. 32-row tiles (r7): +9 us, stage-bound.
//  - global_load_lds (r8): null. GEMM arc closed (~60 us).
//  - k_aggr split-half gather + deg<=16 softmax (r10): null on total (+0.9) —
//    k_aggr not issue-bound; < 60 us, near latency floor.
//  - k1 is NOT BW-bound: r1 sustained 2.65 TB/s on same kernel (248 MB);
//    scatter cost is line-granularity (51 MB writeback for 12.8 MB payload).
//  - THIS ROUND: XCD-ownership edge binning. 8 blocks/chunk; block with
//    blockIdx&7 == dst*8/n processes the edge → all writes to a bucket line
//    come from ONE XCD → its L2 can merge the 4 entries/line. Correct even if
//    the blockIdx%8→XCD heuristic fails (pure perf fallback).
__global__ __launch_bounds__(256, 4) void k_gemm_scatter(
    const float* __restrict__ x, const float* __restrict__ W,
    const float* __restrict__ att, unsigned short* __restrict__ xh16,
    float* __restrict__ s_i, float* __restrict__ s_j, int n, int GB,
    const int* __restrict__ ei, const float* __restrict__ edge_attr,
    const float* __restrict__ We, int* __restrict__ cnt, int4* __restrict__ bucket,
    int slots, int E) {
    if (blockIdx.x >= GB) {
        __shared__ float ceS[32];
        int t = threadIdx.x;
        if (t < 32) {
            int k = t >> 2, h = t & 3;
            float s = 0.f;
            #pragma unroll
            for (int p = 0; p < 4; ++p)
                s += We[k * 16 + h * 4 + p] * att[h * 68 + 64 + p];
            ceS[t] = s;
        }
        __syncthreads();
        int eb = blockIdx.x - GB;
        int grp = eb >> 3;               // 256-edge chunk, covered by 8 blocks
        int own = blockIdx.x & 7;        // physical-XCD guess (round-robin)
        int e = grp * 256 + t;
        if (e < E) {
            int dst = ei[E + e];
            int rng = (int)(((long long)dst * 8) / n);   // dst range 0..7
            if (rng == own) {
                float4 ea0 = *(const float4*)(edge_attr + (size_t)e * 8);
                float4 ea1 = *(const float4*)(edge_attr + (size_t)e * 8 + 4);
                float eav[8] = {ea0.x, ea0.y, ea0.z, ea0.w,
                                ea1.x, ea1.y, ea1.z, ea1.w};
                float se[4];
                #pragma unroll
                for (int h = 0; h < 4; ++h) {
                    float s = 0.f;
                    #pragma unroll
                    for (int k = 0; k < 8; ++k) s += eav[k] * ceS[k * 4 + h];
                    se[h] = s;
                }
                int src = ei[e];
                int4 ent;
                ent.x = src;
                ent.y = (int)pack_h2(se[0], se[1]);
                ent.z = (int)pack_h2(se[2], se[3]);
                ent.w = 0;
                int p = atomicAdd(&cnt[dst], 1);
                if (p < slots) bucket[(size_t)dst * slots + p] = ent;
            }
        }
        return;
    }
    __shared__ float wS[32 * 128];   // 16 KB, [k][col] — conflict-free layout
    __shared__ float xS[64 * 32];    // 8 KB,  [row][k]
    int t = threadIdx.x;
    int c4 = t & 31;                 // this thread owns cols 4*c4 .. 4*c4+3
    int rg = t >> 5;
    int r0 = blockIdx.x * 64;

    float acc[8][4];
    #pragma unroll
    for (int r = 0; r < 8; ++r)
        #pragma unroll
        for (int j = 0; j < 4; ++j) acc[r][j] = 0.f;

    for (int ch = 0; ch < 4; ++ch) {
        {
            const float4* Wv = (const float4*)(W + (size_t)ch * 32 * 128);
            #pragma unroll
            for (int i = 0; i < 4; ++i)
                ((float4*)wS)[t + i * 256] = Wv[t + i * 256];
        }
        #pragma unroll
        for (int i = 0; i < 2; ++i) {
            int idx = t + i * 256;
            int r = idx >> 3;
            int q = idx & 7;
            int row = r0 + r;
            float4 v = make_float4(0.f, 0.f, 0.f, 0.f);
            if (row < n) v = *(const float4*)(x + (size_t)row * 128 + ch * 32 + q * 4);
            ((float4*)xS)[idx] = v;
        }
        __syncthreads();
        #pragma unroll 1
        for (int q = 0; q < 8; ++q) {
            float4 wv0 = *(const float4*)&wS[(4 * q + 0) * 128 + 4 * c4];
            float4 wv1 = *(const float4*)&wS[(4 * q + 1) * 128 + 4 * c4];
            float4 wv2 = *(const float4*)&wS[(4 * q + 2) * 128 + 4 * c4];
            float4 wv3 = *(const float4*)&wS[(4 * q + 3) * 128 + 4 * c4];
            #pragma unroll
            for (int r = 0; r < 8; ++r) {
                float4 xv = ((const float4*)xS)[(rg * 8 + r) * 8 + q];
                acc[r][0] += xv.x * wv0.x + xv.y * wv1.x + xv.z * wv2.x + xv.w * wv3.x;
                acc[r][1] += xv.x * wv0.y + xv.y * wv1.y + xv.z * wv2.y + xv.w * wv3.y;
                acc[r][2] += xv.x * wv0.z + xv.y * wv1.z + xv.z * wv2.z + xv.w * wv3.z;
                acc[r][3] += xv.x * wv0.w + xv.y * wv1.w + xv.z * wv2.w + xv.w * wv3.w;
            }
        }
        __syncthreads();
    }

    // cols 4*c4+j all lie in head h = c4>>3 (4-col groups never straddle heads)
    int h = c4 >> 3;
    int cb = 4 * (c4 & 7);           // col offset within head
    float ai[4], aj[4];
    #pragma unroll
    for (int j = 0; j < 4; ++j) {
        ai[j] = att[h * 68 + cb + j];
        aj[j] = att[h * 68 + 32 + cb + j];
    }
    #pragma unroll 1
    for (int r = 0; r < 8; ++r) {
        int row = r0 + rg * 8 + r;
        bool ok = row < n;
        if (ok) {
            ushort4 us;
            us.x = f2bf(acc[r][0]);
            us.y = f2bf(acc[r][1]);
            us.z = f2bf(acc[r][2]);
            us.w = f2bf(acc[r][3]);
            *(ushort4*)(xh16 + (size_t)row * 128 + 4 * c4) = us;
        }
        float pi = acc[r][0] * ai[0] + acc[r][1] * ai[1]
                 + acc[r][2] * ai[2] + acc[r][3] * ai[3];
        float pj = acc[r][0] * aj[0] + acc[r][1] * aj[1]
                 + acc[r][2] * aj[2] + acc[r][3] * aj[3];
        // reduce the 8 lanes of each head group
        #pragma unroll
        for (int m = 1; m < 8; m <<= 1) {
            pi += __shfl_xor(pi, m);
            pj += __shfl_xor(pj, m);
        }
        if ((c4 & 7) == 0 && ok) {   // lanes h*8: one head each, 4 B stores
            s_i[(size_t)row * 4 + h] = pi;
            s_j[(size_t)row * 4 + h] = pj;
        }
    }
}

// One wave per node. Phase 1: lane = slot (all 4 heads/lane), softmax with
// deg<=16 fast path. Phase 2 (gather): lane = 32*half + c; each lane reads
// 8 B (channels 4c..4c+3) of edge j0+2j+half; shfl_xor(32) merges halves.
__global__ __launch_bounds__(256) void k_aggr(
    const int* __restrict__ cnt, const int4* __restrict__ bucket, int slots,
    const float* __restrict__ s_i, const float* __restrict__ s_j,
    const unsigned* __restrict__ xh32, const float* __restrict__ bias,
    float* __restrict__ out, int n) {
    __shared__ float wbuf[4][64][4];
    __shared__ int sbuf[4][64];
    int wid = threadIdx.x >> 6;
    int l = threadIdx.x & 63;
    int node = blockIdx.x * 4 + wid;
    if (node >= n) return;
    int deg = cnt[node];
    deg = deg < slots ? deg : slots;
    int c = l & 31;                  // uint2 column: channels 4c..4c+3
    if (deg == 0) {
        if (l < 32) {
            float4 b4 = ((const float4*)bias)[c];
            *(float4*)(out + (size_t)node * 128 + c * 4) = b4;
        }
        return;
    }

    float4 si4 = *(const float4*)(s_i + (size_t)node * 4);
    float lg[4];
    int src = 0;
    bool valid = l < deg;
    if (valid) {
        int4 ent = bucket[(size_t)node * slots + l];
        src = ent.x;
        float4 sj4 = *(const float4*)(s_j + (size_t)src * 4);
        __half2 se01 = *(__half2*)&ent.y;
        __half2 se23 = *(__half2*)&ent.z;
        float2 se01f = __half22float2(se01);
        float2 se23f = __half22float2(se23);
        float a;
        a = si4.x + sj4.x + se01f.x; lg[0] = a > 0.f ? a : NEG_SLOPE * a;
        a = si4.y + sj4.y + se01f.y; lg[1] = a > 0.f ? a : NEG_SLOPE * a;
        a = si4.z + sj4.z + se23f.x; lg[2] = a > 0.f ? a : NEG_SLOPE * a;
        a = si4.w + sj4.w + se23f.y; lg[3] = a > 0.f ? a : NEG_SLOPE * a;
    } else {
        lg[0] = lg[1] = lg[2] = lg[3] = -INFINITY;
    }
    float mx[4];
    #pragma unroll
    for (int h = 0; h < 4; ++h) mx[h] = lg[h];
    #pragma unroll
    for (int m = 1; m < 16; m <<= 1)
        #pragma unroll
        for (int h = 0; h < 4; ++h) mx[h] = fmaxf(mx[h], __shfl_xor(mx[h], m));
    if (deg > 16) {
        #pragma unroll
        for (int m = 16; m < 64; m <<= 1)
            #pragma unroll
            for (int h = 0; h < 4; ++h) mx[h] = fmaxf(mx[h], __shfl_xor(mx[h], m));
    }
    float w[4], sm[4];
    #pragma unroll
    for (int h = 0; h < 4; ++h) {
        w[h] = valid ? __expf(lg[h] - mx[h]) : 0.f;
        sm[h] = w[h];
    }
    #pragma unroll
    for (int m = 1; m < 16; m <<= 1)
        #pragma unroll
        for (int h = 0; h < 4; ++h) sm[h] += __shfl_xor(sm[h], m);
    if (deg > 16) {
        #pragma unroll
        for (int m = 16; m < 64; m <<= 1)
            #pragma unroll
            for (int h = 0; h < 4; ++h) sm[h] += __shfl_xor(sm[h], m);
    }
    #pragma unroll
    for (int h = 0; h < 4; ++h) w[h] *= 1.f / (sm[h] + 1e-16f);

    *(float4*)&wbuf[wid][l][0] = make_float4(w[0], w[1], w[2], w[3]);
    sbuf[wid][l] = src;
    // same-wave LDS producer/consumer: no barrier needed, lgkmcnt handles it

    int p2 = l >> 5;                 // half: even/odd edge
    int hsel = c >> 3;               // head of channels 4c..4c+3
    const uint2* xh64 = (const uint2*)xh32;
    float a0 = 0.f, a1 = 0.f, a2 = 0.f, a3 = 0.f;
    for (int j0 = 0; j0 < deg; j0 += 16) {
        int srcs[8];
        float ws[8];
        #pragma unroll
        for (int j = 0; j < 8; ++j) {
            int jp = j0 + 2 * j + p2;
            int jj = jp < deg ? jp : 0;
            bool in = jp < deg;
            srcs[j] = sbuf[wid][jj];
            ws[j] = in ? wbuf[wid][jj][hsel] : 0.f;
        }
        uint2 u[8];
        #pragma unroll
        for (int j = 0; j < 8; ++j) u[j] = xh64[(size_t)srcs[j] * 32 + c];
        #pragma unroll
        for (int j = 0; j < 8; ++j) {
            a0 += ws[j] * __uint_as_float(u[j].x << 16);
            a1 += ws[j] * __uint_as_float(u[j].x & 0xffff0000u);
            a2 += ws[j] * __uint_as_float(u[j].y << 16);
            a3 += ws[j] * __uint_as_float(u[j].y & 0xffff0000u);
        }
    }
    a0 += __shfl_xor(a0, 32);
    a1 += __shfl_xor(a1, 32);
    a2 += __shfl_xor(a2, 32);
    a3 += __shfl_xor(a3, 32);
    if (l < 32) {
        float4 b4 = ((const float4*)bias)[c];
        *(float4*)(out + (size_t)node * 128 + c * 4) =
            make_float4(a0 + b4.x, a1 + b4.y, a2 + b4.z, a3 + b4.w);
    }
}

extern "C" void kernel_launch(void* const* d_in, const int* in_sizes, int n_in,
                              void* d_out, int out_size, void* d_ws, size_t ws_size,
                              hipStream_t stream) {
    const float* x    = (const float*)d_in[0];
    const int*   ei   = (const int*)d_in[1];
    const float* eattr= (const float*)d_in[2];
    const float* W    = (const float*)d_in[3];
    const float* We   = (const float*)d_in[4];
    const float* att  = (const float*)d_in[5];
    const float* bias = (const float*)d_in[6];
    float* out = (float*)d_out;
    int n = in_sizes[0] / 128;
    int E = in_sizes[1] / 2;

    char* w = (char*)d_ws;
    auto alloc = [&](size_t bytes) {
        char* p = w;
        w += (bytes + 255) & ~(size_t)255;
        return (void*)p;
    };
    unsigned short* xh16 = (unsigned short*)alloc((size_t)n * 128 * 2);
    float* s_i           = (float*)alloc((size_t)n * 16);
    float* s_j           = (float*)alloc((size_t)n * 16);
    int* cnt             = (int*)alloc((size_t)n * 4);
    size_t remain = (ws_size > (size_t)(w - (char*)d_ws))
                  ? ws_size - (size_t)(w - (char*)d_ws) : 0;
    int slots = (int)(remain / ((size_t)n * 16));
    if (slots > 64) slots = 64;
    if (slots < 32) slots = 32;
    int4* bucket         = (int4*)alloc((size_t)n * slots * 16);

    int GB = (n + 63) / 64;
    int EB = ((E + 255) / 256) * 8;   // 8 ownership blocks per 256-edge chunk

    (void)hipMemsetAsync(cnt, 0, (size_t)n * 4, stream);
    k_gemm_scatter<<<GB + EB, 256, 0, stream>>>(x, W, att, xh16, s_i, s_j, n, GB,
                                                ei, eattr, We, cnt, bucket, slots, E);
    k_aggr<<<(n + 3) / 4, 256, 0, stream>>>(cnt, bucket, slots, s_i, s_j,
                                            (const unsigned*)xh16, bias, out, n);
}

// Round 12
// 191.732 us; speedup vs baseline: 1.1489x; 1.1489x over previous
//
#include <hip/hip_runtime.h>
#include <hip/hip_fp16.h>
#include <stdint.h>
#include <math.h>

#define NEG_SLOPE 0.2f

static __device__ __forceinline__ unsigned short f2bf(float f) {
    unsigned u = __float_as_uint(f);
    unsigned r = (u + 0x7FFFu + ((u >> 16) & 1u)) >> 16;
    return (unsigned short)r;
}
static __device__ __forceinline__ unsigned pack_h2(float a, float b) {
    __half2 h = __floats2half2_rn(a, b);
    return *(unsigned*)&h;
}

// FINAL LEDGER (all arcs closed; this file = r5, best measured 188.4 us):
//  - (256,6) launch bounds: VGPR cap 40 → acc spills, +135 MB TCC (r1).
//  - 4 B bucket entries + erec indirection: scattered stores cost a full 64 B
//    line regardless of entry size; cross-XCD entries never merge (r2).
//  - W^T LDS + swizzle: bank conflicts, +7.5 us (r3). Keep wS[k][col].
//  - Kernel split (r4): +28 us — edge blocks must backfill GEMM latency slack.
//    Attribution: gemm 52 us standalone, 6% HBM / 33% VALU / 18.8% occ.
//  - b128 W-reads (r5): −2 us. k1 = 60.2 us. BEST.
//  - Reg-staged double-buffer (r6): regalloc spills, +10 us.
//  - 32-row tiles (r7): occupancy 33→49% but +9 us — stage-phase-bound.
//  - global_load_lds DMA (r8): null. GEMM arc closed.
//  - split-half gather + deg<=16 softmax (r10): null — k_aggr latency-floor.
//  - XCD-ownership binning (r11): WRITE only −2.5 MB (same-XCD scatter still
//    doesn't merge), FETCH +50 MB, +36 us. Scatter floor is HW-structural.
//  - Floor arithmetic: k1 ~60 (incl ~35 us structural scatter writeback)
//    + k_aggr ~50 (random-gather latency) + harness reset ~76 = ~186 us;
//    best measured 188.4 us (+1.3%).
__global__ __launch_bounds__(256, 4) void k_gemm_scatter(
    const float* __restrict__ x, const float* __restrict__ W,
    const float* __restrict__ att, unsigned short* __restrict__ xh16,
    float* __restrict__ s_i, float* __restrict__ s_j, int n, int GB,
    const int* __restrict__ ei, const float* __restrict__ edge_attr,
    const float* __restrict__ We, int* __restrict__ cnt, int4* __restrict__ bucket,
    int slots, int E) {
    if (blockIdx.x >= GB) {
        __shared__ float ceS[32];
        int t = threadIdx.x;
        if (t < 32) {
            int k = t >> 2, h = t & 3;
            float s = 0.f;
            #pragma unroll
            for (int p = 0; p < 4; ++p)
                s += We[k * 16 + h * 4 + p] * att[h * 68 + 64 + p];
            ceS[t] = s;
        }
        __syncthreads();
        int e = (blockIdx.x - GB) * 256 + t;
        if (e < E) {
            float4 ea0 = *(const float4*)(edge_attr + (size_t)e * 8);
            float4 ea1 = *(const float4*)(edge_attr + (size_t)e * 8 + 4);
            float eav[8] = {ea0.x, ea0.y, ea0.z, ea0.w, ea1.x, ea1.y, ea1.z, ea1.w};
            float se[4];
            #pragma unroll
            for (int h = 0; h < 4; ++h) {
                float s = 0.f;
                #pragma unroll
                for (int k = 0; k < 8; ++k) s += eav[k] * ceS[k * 4 + h];
                se[h] = s;
            }
            int src = ei[e], dst = ei[E + e];
            int4 ent;
            ent.x = src;
            ent.y = (int)pack_h2(se[0], se[1]);
            ent.z = (int)pack_h2(se[2], se[3]);
            ent.w = 0;
            int p = atomicAdd(&cnt[dst], 1);
            if (p < slots) bucket[(size_t)dst * slots + p] = ent;
        }
        return;
    }
    __shared__ float wS[32 * 128];   // 16 KB, [k][col] — conflict-free layout
    __shared__ float xS[64 * 32];    // 8 KB,  [row][k]
    int t = threadIdx.x;
    int c4 = t & 31;                 // this thread owns cols 4*c4 .. 4*c4+3
    int rg = t >> 5;
    int r0 = blockIdx.x * 64;

    float acc[8][4];
    #pragma unroll
    for (int r = 0; r < 8; ++r)
        #pragma unroll
        for (int j = 0; j < 4; ++j) acc[r][j] = 0.f;

    for (int ch = 0; ch < 4; ++ch) {
        {
            const float4* Wv = (const float4*)(W + (size_t)ch * 32 * 128);
            #pragma unroll
            for (int i = 0; i < 4; ++i)
                ((float4*)wS)[t + i * 256] = Wv[t + i * 256];
        }
        #pragma unroll
        for (int i = 0; i < 2; ++i) {
            int idx = t + i * 256;
            int r = idx >> 3;
            int q = idx & 7;
            int row = r0 + r;
            float4 v = make_float4(0.f, 0.f, 0.f, 0.f);
            if (row < n) v = *(const float4*)(x + (size_t)row * 128 + ch * 32 + q * 4);
            ((float4*)xS)[idx] = v;
        }
        __syncthreads();
        #pragma unroll 1
        for (int q = 0; q < 8; ++q) {
            float4 wv0 = *(const float4*)&wS[(4 * q + 0) * 128 + 4 * c4];
            float4 wv1 = *(const float4*)&wS[(4 * q + 1) * 128 + 4 * c4];
            float4 wv2 = *(const float4*)&wS[(4 * q + 2) * 128 + 4 * c4];
            float4 wv3 = *(const float4*)&wS[(4 * q + 3) * 128 + 4 * c4];
            #pragma unroll
            for (int r = 0; r < 8; ++r) {
                float4 xv = ((const float4*)xS)[(rg * 8 + r) * 8 + q];
                acc[r][0] += xv.x * wv0.x + xv.y * wv1.x + xv.z * wv2.x + xv.w * wv3.x;
                acc[r][1] += xv.x * wv0.y + xv.y * wv1.y + xv.z * wv2.y + xv.w * wv3.y;
                acc[r][2] += xv.x * wv0.z + xv.y * wv1.z + xv.z * wv2.z + xv.w * wv3.z;
                acc[r][3] += xv.x * wv0.w + xv.y * wv1.w + xv.z * wv2.w + xv.w * wv3.w;
            }
        }
        __syncthreads();
    }

    // cols 4*c4+j all lie in head h = c4>>3 (4-col groups never straddle heads)
    int h = c4 >> 3;
    int cb = 4 * (c4 & 7);           // col offset within head
    float ai[4], aj[4];
    #pragma unroll
    for (int j = 0; j < 4; ++j) {
        ai[j] = att[h * 68 + cb + j];
        aj[j] = att[h * 68 + 32 + cb + j];
    }
    #pragma unroll 1
    for (int r = 0; r < 8; ++r) {
        int row = r0 + rg * 8 + r;
        bool ok = row < n;
        if (ok) {
            ushort4 us;
            us.x = f2bf(acc[r][0]);
            us.y = f2bf(acc[r][1]);
            us.z = f2bf(acc[r][2]);
            us.w = f2bf(acc[r][3]);
            *(ushort4*)(xh16 + (size_t)row * 128 + 4 * c4) = us;
        }
        float pi = acc[r][0] * ai[0] + acc[r][1] * ai[1]
                 + acc[r][2] * ai[2] + acc[r][3] * ai[3];
        float pj = acc[r][0] * aj[0] + acc[r][1] * aj[1]
                 + acc[r][2] * aj[2] + acc[r][3] * aj[3];
        // reduce the 8 lanes of each head group
        #pragma unroll
        for (int m = 1; m < 8; m <<= 1) {
            pi += __shfl_xor(pi, m);
            pj += __shfl_xor(pj, m);
        }
        if ((c4 & 7) == 0 && ok) {   // lanes h*8: one head each, 4 B stores
            s_i[(size_t)row * 4 + h] = pi;
            s_j[(size_t)row * 4 + h] = pj;
        }
    }
}

// One wave per node. Lane = slot (all 4 heads per lane): coalesced bucket read
// + one random s_j read. Weights/srcs staged in LDS; gather 8-deep in flight.
__global__ __launch_bounds__(256) void k_aggr(
    const int* __restrict__ cnt, const int4* __restrict__ bucket, int slots,
    const float* __restrict__ s_i, const float* __restrict__ s_j,
    const unsigned* __restrict__ xh32, const float* __restrict__ bias,
    float* __restrict__ out, int n) {
    __shared__ float wbuf[4][64][4];
    __shared__ int sbuf[4][64];
    int wid = threadIdx.x >> 6;
    int l = threadIdx.x & 63;
    int node = blockIdx.x * 4 + wid;
    if (node >= n) return;
    int deg = cnt[node];
    deg = deg < slots ? deg : slots;
    float2 b = ((const float2*)bias)[l];
    float2* op = (float2*)(out + (size_t)node * 128);
    if (deg == 0) { op[l] = b; return; }

    float4 si4 = *(const float4*)(s_i + (size_t)node * 4);
    float lg[4];
    int src = 0;
    bool valid = l < deg;
    if (valid) {
        int4 ent = bucket[(size_t)node * slots + l];
        src = ent.x;
        float4 sj4 = *(const float4*)(s_j + (size_t)src * 4);
        __half2 se01 = *(__half2*)&ent.y;
        __half2 se23 = *(__half2*)&ent.z;
        float2 se01f = __half22float2(se01);
        float2 se23f = __half22float2(se23);
        float a;
        a = si4.x + sj4.x + se01f.x; lg[0] = a > 0.f ? a : NEG_SLOPE * a;
        a = si4.y + sj4.y + se01f.y; lg[1] = a > 0.f ? a : NEG_SLOPE * a;
        a = si4.z + sj4.z + se23f.x; lg[2] = a > 0.f ? a : NEG_SLOPE * a;
        a = si4.w + sj4.w + se23f.y; lg[3] = a > 0.f ? a : NEG_SLOPE * a;
    } else {
        lg[0] = lg[1] = lg[2] = lg[3] = -INFINITY;
    }
    float mx[4];
    #pragma unroll
    for (int h = 0; h < 4; ++h) mx[h] = lg[h];
    #pragma unroll
    for (int m = 1; m < 64; m <<= 1)
        #pragma unroll
        for (int h = 0; h < 4; ++h) mx[h] = fmaxf(mx[h], __shfl_xor(mx[h], m));
    float w[4], sm[4];
    #pragma unroll
    for (int h = 0; h < 4; ++h) {
        w[h] = valid ? __expf(lg[h] - mx[h]) : 0.f;
        sm[h] = w[h];
    }
    #pragma unroll
    for (int m = 1; m < 64; m <<= 1)
        #pragma unroll
        for (int h = 0; h < 4; ++h) sm[h] += __shfl_xor(sm[h], m);
    #pragma unroll
    for (int h = 0; h < 4; ++h) w[h] *= 1.f / (sm[h] + 1e-16f);

    *(float4*)&wbuf[wid][l][0] = make_float4(w[0], w[1], w[2], w[3]);
    sbuf[wid][l] = src;
    // same-wave LDS producer/consumer: no barrier needed, lgkmcnt handles it

    int hsel = l >> 4;   // head of packed channels 2l, 2l+1
    float a0 = 0.f, a1 = 0.f;
    for (int j0 = 0; j0 < deg; j0 += 8) {
        int srcs[8];
        float ws[8];
        #pragma unroll
        for (int j = 0; j < 8; ++j) {
            int jj = j0 + j < deg ? j0 + j : 0;
            bool in = j0 + j < deg;
            srcs[j] = sbuf[wid][jj];
            ws[j] = in ? wbuf[wid][jj][hsel] : 0.f;
        }
        unsigned u[8];
        #pragma unroll
        for (int j = 0; j < 8; ++j) u[j] = xh32[(size_t)srcs[j] * 64 + l];
        #pragma unroll
        for (int j = 0; j < 8; ++j) {
            a0 += ws[j] * __uint_as_float(u[j] << 16);
            a1 += ws[j] * __uint_as_float(u[j] & 0xffff0000u);
        }
    }
    op[l] = make_float2(a0 + b.x, a1 + b.y);
}

extern "C" void kernel_launch(void* const* d_in, const int* in_sizes, int n_in,
                              void* d_out, int out_size, void* d_ws, size_t ws_size,
                              hipStream_t stream) {
    const float* x    = (const float*)d_in[0];
    const int*   ei   = (const int*)d_in[1];
    const float* eattr= (const float*)d_in[2];
    const float* W    = (const float*)d_in[3];
    const float* We   = (const float*)d_in[4];
    const float* att  = (const float*)d_in[5];
    const float* bias = (const float*)d_in[6];
    float* out = (float*)d_out;
    int n = in_sizes[0] / 128;
    int E = in_sizes[1] / 2;

    char* w = (char*)d_ws;
    auto alloc = [&](size_t bytes) {
        char* p = w;
        w += (bytes + 255) & ~(size_t)255;
        return (void*)p;
    };
    unsigned short* xh16 = (unsigned short*)alloc((size_t)n * 128 * 2);
    float* s_i           = (float*)alloc((size_t)n * 16);
    float* s_j           = (float*)alloc((size_t)n * 16);
    int* cnt             = (int*)alloc((size_t)n * 4);
    size_t remain = (ws_size > (size_t)(w - (char*)d_ws))
                  ? ws_size - (size_t)(w - (char*)d_ws) : 0;
    int slots = (int)(remain / ((size_t)n * 16));
    if (slots > 64) slots = 64;
    if (slots < 32) slots = 32;
    int4* bucket         = (int4*)alloc((size_t)n * slots * 16);

    int GB = (n + 63) / 64;
    int EB = (E + 255) / 256;

    (void)hipMemsetAsync(cnt, 0, (size_t)n * 4, stream);
    k_gemm_scatter<<<GB + EB, 256, 0, stream>>>(x, W, att, xh16, s_i, s_j, n, GB,
                                                ei, eattr, We, cnt, bucket, slots, E);
    k_aggr<<<(n + 3) / 4, 256, 0, stream>>>(cnt, bucket, slots, s_i, s_j,
                                            (const unsigned*)xh16, bias, out, n);
}